// Round 11
// baseline (716.422 us; speedup 1.0000x reference)
//
#include <hip/hip_runtime.h>

// ---------------------------------------------------------------------------
// GFGCN round 13: R9 base (best, 696us) + deferred additive wins.
//  - SP 8->4: P traffic 32+32 -> 16+16 MB per sgemm/reduce pair (~-190 MB
//    total). R4(2/CU)==R5(4/CU) proved sgemm is occupancy-insensitive here.
//  - W-GEMM layers 1/2: MF=1, grid (2,128)=256 blocks (was 128 = 0.5/CU).
//  - 3 weight transposes fused into 1 launch.
// sgemm_lds / pack_S / reduce / combine byte-identical to R9.
// The ~2 TB/s sgemm band is invariant to every schedule/layout/staging
// lever tried (R3-R12) with HBM at ~30% during sgemms -- rate levers
// exhausted at HIP source level; this round removes bytes and launches.
// ---------------------------------------------------------------------------

typedef __attribute__((ext_vector_type(4))) float  f32x4;
typedef __attribute__((ext_vector_type(8))) __bf16 bf16x8;
typedef __attribute__((ext_vector_type(4))) __bf16 bf16x4;

__device__ __forceinline__ void gload_lds16(const __bf16* g, __bf16* l) {
    __builtin_amdgcn_global_load_lds(
        (const __attribute__((address_space(1))) void*)g,
        (__attribute__((address_space(3))) void*)l, 16, 0, 0);
}

// ---------------------------------------------------------------------------
// pack_S (verbatim R9): fp32 S -> bf16 packed tiles, tile(m,z) = rows
// [64m,64m+64) x cols[z*KCH,(z+1)*KCH), record(st)=2048 elems: slot t=4*rt+q
// holds S[64m+rt][zKCH+st*32+((q^s(rt))*8)..+8], s(rt)=(rt>>1)&3.
// ---------------------------------------------------------------------------
__global__ __launch_bounds__(256)
void pack_S(const float* __restrict__ S, __bf16* __restrict__ Spk,
            int KCH, int SP) {
    __shared__ __bf16 L[8][1032];
    const int t = threadIdx.x;
    const int m = blockIdx.x, z = blockIdx.y;
    __bf16* tile = Spk + ((size_t)m * SP + z) * ((size_t)64 * KCH);

    const int rl    = t & 7;
    const int cstep = t >> 3;
    const int stl0  = t >> 5;
    const int slot  = t & 31;
    const int rs    = slot >> 2;
    const int q     = slot & 3;

    for (int r0 = 0; r0 < 64; r0 += 8) {
        const int rg_st = r0 + rs;
        const int qq    = q ^ ((rg_st >> 1) & 3);
        for (int c1 = 0; c1 < KCH; c1 += 1024) {
            const float* src = S + (size_t)(m * 64 + r0 + rl) * 8192
                                 + (size_t)z * KCH + c1 + cstep * 32;
            #pragma unroll
            for (int j = 0; j < 4; j++) {
                float4 f0 = *(const float4*)(src + j * 8);
                float4 f1 = *(const float4*)(src + j * 8 + 4);
                bf16x8 v;
                v[0]=(__bf16)f0.x; v[1]=(__bf16)f0.y; v[2]=(__bf16)f0.z; v[3]=(__bf16)f0.w;
                v[4]=(__bf16)f1.x; v[5]=(__bf16)f1.y; v[6]=(__bf16)f1.z; v[7]=(__bf16)f1.w;
                *(bf16x8*)&L[rl][cstep * 32 + j * 8] = v;
            }
            __syncthreads();
            #pragma unroll
            for (int k2 = 0; k2 < 4; k2++) {
                const int stl = stl0 + k2 * 8;
                bf16x8 v = *(const bf16x8*)&L[rs][stl * 32 + qq * 8];
                *(bf16x8*)(tile + (size_t)((c1 >> 5) + stl) * 2048
                                + (size_t)(r0 * 4 + slot) * 8) = v;
            }
            __syncthreads();
        }
    }
}

// ---- all three weight transposes in one launch ----
__global__ void cvt_transpose3(const float* __restrict__ W1, __bf16* __restrict__ W1t,
                               const float* __restrict__ W2, __bf16* __restrict__ W2t,
                               const float* __restrict__ W3, __bf16* __restrict__ W3t) {
    const int i = blockIdx.x * blockDim.x + threadIdx.x;
    if (i < 65536) {                       // W1: 512x128
        int k = i >> 7, m = i & 127;
        W1t[(size_t)m * 512 + k] = (__bf16)W1[i];
    } else if (i < 65536 + 16384) {        // W2: 128x128
        int j = i - 65536;
        int k = j >> 7, m = j & 127;
        W2t[(size_t)m * 128 + k] = (__bf16)W2[j];
    } else if (i < 65536 + 16384 + 8192) { // W3: 128x64
        int j = i - 81920;
        int k = j >> 6, m = j & 63;
        W3t[(size_t)m * 128 + k] = (__bf16)W3[j];
    }
}

// ---------------------------------------------------------------------------
// Register-direct GEMM for W-GEMMs (verbatim R9). BF32=1: B operand fp32.
// ---------------------------------------------------------------------------
template<int MF, int NF, int OUTMODE, int BF32>
__global__ __launch_bounds__(256)
void gemm_rd(const __bf16* __restrict__ A, const void* __restrict__ Bv,
             void* __restrict__ out, int K, int Kchunk, int Mtot, int Ntot)
{
    const int lane = threadIdx.x & 63;
    const int w    = threadIdx.x >> 6;
    const int l15  = lane & 15;
    const int quad = lane >> 4;

    const int m_base = blockIdx.x * (64 * MF) + w * (16 * MF);
    const int n_base = blockIdx.y * (16 * NF);
    const int kstart = blockIdx.z * Kchunk;

    const __bf16* Ap[MF];
    #pragma unroll
    for (int mf = 0; mf < MF; mf++)
        Ap[mf] = A + (size_t)(m_base + mf * 16 + l15) * K + kstart + quad * 8;

    const __bf16* Bp[NF];
    const float*  Bpf[NF];
    #pragma unroll
    for (int nf = 0; nf < NF; nf++) {
        const size_t roff = (size_t)(n_base + nf * 16 + l15) * K + kstart + quad * 8;
        if (BF32) Bpf[nf] = (const float*)Bv + roff;
        else      Bp[nf]  = (const __bf16*)Bv + roff;
    }

    f32x4 acc[MF][NF];
    #pragma unroll
    for (int mf = 0; mf < MF; mf++)
        #pragma unroll
        for (int nf = 0; nf < NF; nf++)
            acc[mf][nf] = (f32x4){0.f, 0.f, 0.f, 0.f};

    #pragma unroll 2
    for (int ks = 0; ks < Kchunk; ks += 32) {
        bf16x8 a[MF], b[NF];
        #pragma unroll
        for (int mf = 0; mf < MF; mf++) a[mf] = *(const bf16x8*)(Ap[mf] + ks);
        #pragma unroll
        for (int nf = 0; nf < NF; nf++) {
            if (BF32) {
                float4 f0 = *(const float4*)(Bpf[nf] + ks);
                float4 f1 = *(const float4*)(Bpf[nf] + ks + 4);
                bf16x8 tt;
                tt[0] = (__bf16)f0.x; tt[1] = (__bf16)f0.y;
                tt[2] = (__bf16)f0.z; tt[3] = (__bf16)f0.w;
                tt[4] = (__bf16)f1.x; tt[5] = (__bf16)f1.y;
                tt[6] = (__bf16)f1.z; tt[7] = (__bf16)f1.w;
                b[nf] = tt;
            } else {
                b[nf] = *(const bf16x8*)(Bp[nf] + ks);
            }
        }
        #pragma unroll
        for (int mf = 0; mf < MF; mf++)
            #pragma unroll
            for (int nf = 0; nf < NF; nf++)
                acc[mf][nf] = __builtin_amdgcn_mfma_f32_16x16x32_bf16(
                    a[mf], b[nf], acc[mf][nf], 0, 0, 0);
    }

    if (OUTMODE == 0) {
        float* P = (float*)out + (size_t)blockIdx.z * Mtot * Ntot;
        #pragma unroll
        for (int mf = 0; mf < MF; mf++) {
            const int rowb = m_base + mf * 16 + quad * 4;
            #pragma unroll
            for (int nf = 0; nf < NF; nf++) {
                const int col = n_base + nf * 16 + l15;
                *(f32x4*)(P + (size_t)col * Mtot + rowb) = acc[mf][nf];
            }
        }
    } else {
        __bf16* O = (__bf16*)out;
        #pragma unroll
        for (int mf = 0; mf < MF; mf++) {
            const int rowb = m_base + mf * 16 + quad * 4;
            #pragma unroll
            for (int nf = 0; nf < NF; nf++) {
                const int col = n_base + nf * 16 + l15;
                #pragma unroll
                for (int r = 0; r < 4; r++)
                    O[(size_t)(rowb + r) * Ntot + col] = (__bf16)acc[mf][nf][r];
            }
        }
    }
}

// ---------------------------------------------------------------------------
// S-GEMM (verbatim R9): 3-deep counted-vmcnt pipeline; A streams contiguously
// from the packed tile. BM=64, BN=32*NFW, BK=32, 2x2 waves, LDS 36KB.
// Output: fp32 partials, t-layout P[z][col][row], rows contiguous (f32x4).
// ---------------------------------------------------------------------------
template<int NFW>
__global__ __launch_bounds__(256)
void sgemm_lds(const __bf16* __restrict__ Spk, const __bf16* __restrict__ Bt,
               float* __restrict__ P, int Kb, int Kchunk, int Mtot)
{
    constexpr int BN = 32 * NFW;               // 128 or 64
    __shared__ __bf16 Asm[3][64 * 32];         // 4KB per buf
    __shared__ __bf16 Bsm[3][BN * 32];         // 8KB (NFW=4) per buf

    const int t    = threadIdx.x;              // 0..255
    const int lane = t & 63;
    const int w    = t >> 6;
    const int wm   = w >> 1;                   // 0..1 (M)
    const int wn   = w & 1;                    // 0..1 (N)
    const int l15  = lane & 15;
    const int quad = lane >> 4;

    const int m_block = blockIdx.x * 64;
    const int kstart  = blockIdx.z * Kchunk;
    const int nst     = Kchunk >> 5;           // BK=32 steps

    // A: contiguous packed tile stream
    const __bf16* gApk = Spk
        + ((size_t)blockIdx.x * gridDim.z + blockIdx.z) * ((size_t)64 * Kchunk);

    // B staging: thread t owns LDS chunk (row=t>>2, q=t&3); source swizzled
    const int rt  = t >> 2;
    const int qs  = (t & 3) ^ ((rt >> 1) & 3);
    const __bf16* gB0 = Bt + (size_t)rt * Kb        + kstart + qs * 8;
    const __bf16* gB1 = Bt + (size_t)(64 + rt) * Kb + kstart + qs * 8;

    f32x4 acc[2][NFW];
    #pragma unroll
    for (int mf = 0; mf < 2; mf++)
        #pragma unroll
        for (int nf = 0; nf < NFW; nf++)
            acc[mf][nf] = (f32x4){0.f, 0.f, 0.f, 0.f};

    auto stage = [&](int buf, int st) {
        gload_lds16(gApk + (size_t)st * 2048 + t * 8, &Asm[buf][t * 8]);
        const int ks = st << 5;
        gload_lds16(gB0 + ks, &Bsm[buf][t * 8]);
        if (NFW == 4)
            gload_lds16(gB1 + ks, &Bsm[buf][2048 + t * 8]);
    };

    // read-side swizzled chunk offsets (k-invariant)
    int aoff[2], boff[NFW];
    #pragma unroll
    for (int mf = 0; mf < 2; mf++) {
        const int ar = wm * 32 + mf * 16 + l15;
        aoff[mf] = ar * 32 + (quad ^ ((ar >> 1) & 3)) * 8;
    }
    #pragma unroll
    for (int nf = 0; nf < NFW; nf++) {
        const int br = wn * 16 * NFW + nf * 16 + l15;
        boff[nf] = br * 32 + (quad ^ ((br >> 1) & 3)) * 8;
    }

    stage(0, 0);
    if (nst > 1) stage(1, 1);
    if (nst > 2) stage(2, 2);

    for (int st = 0; st < nst; ++st) {
        const int rem   = nst - 1 - st;
        const int ahead = rem < 2 ? rem : 2;

        if (ahead == 2) {
            if (NFW == 4) asm volatile("s_waitcnt vmcnt(6)" ::: "memory");
            else          asm volatile("s_waitcnt vmcnt(4)" ::: "memory");
        } else if (ahead == 1) {
            if (NFW == 4) asm volatile("s_waitcnt vmcnt(3)" ::: "memory");
            else          asm volatile("s_waitcnt vmcnt(2)" ::: "memory");
        } else {
            asm volatile("s_waitcnt vmcnt(0)" ::: "memory");
        }
        __builtin_amdgcn_s_barrier();
        asm volatile("" ::: "memory");

        const int buf = st - (st / 3) * 3;     // st % 3
        bf16x8 a[2], b[NFW];
        #pragma unroll
        for (int mf = 0; mf < 2; mf++)
            a[mf] = *(const bf16x8*)&Asm[buf][aoff[mf]];
        #pragma unroll
        for (int nf = 0; nf < NFW; nf++)
            b[nf] = *(const bf16x8*)&Bsm[buf][boff[nf]];

        asm volatile("s_waitcnt lgkmcnt(0)" ::: "memory");
        __builtin_amdgcn_s_barrier();
        asm volatile("" ::: "memory");
        if (st + 3 < nst) stage(buf, st + 3);

        #pragma unroll
        for (int mf = 0; mf < 2; mf++)
            #pragma unroll
            for (int nf = 0; nf < NFW; nf++)
                acc[mf][nf] = __builtin_amdgcn_mfma_f32_16x16x32_bf16(
                    a[mf], b[nf], acc[mf][nf], 0, 0, 0);
    }

    float* Pz = P + (size_t)blockIdx.z * Mtot * BN;
    #pragma unroll
    for (int mf = 0; mf < 2; mf++) {
        const int rowb = m_block + wm * 32 + mf * 16 + quad * 4;
        #pragma unroll
        for (int nf = 0; nf < NFW; nf++) {
            const int col = wn * 16 * NFW + nf * 16 + l15;
            *(f32x4*)(Pz + (size_t)col * Mtot + rowb) = acc[mf][nf];
        }
    }
}

// ---- sum SP split-partials -> bf16 t-layout Y[f][node] ----
__global__ void reduce_partials(const float* __restrict__ P,
                                __bf16* __restrict__ Y, int total4,
                                int SP, int MN) {
    int i = blockIdx.x * blockDim.x + threadIdx.x;
    if (i >= total4) return;
    size_t base = (size_t)i * 4;
    float4 s = *(const float4*)(P + base);
    for (int sp = 1; sp < SP; sp++) {
        float4 v = *(const float4*)(P + (size_t)sp * MN + base);
        s.x += v.x; s.y += v.y; s.z += v.z; s.w += v.w;
    }
    bf16x4 o; o[0] = (__bf16)s.x; o[1] = (__bf16)s.y;
    o[2] = (__bf16)s.z; o[3] = (__bf16)s.w;
    *(bf16x4*)(Y + base) = o;
}

// ---- combine: out[node][f] = act(h0*Y0 + h1*Y1 + h2*sum(P) + b[f]) ----
template<int RELU, int F32OUT>
__global__ void combine_out(const float* __restrict__ P,
                            const __bf16* __restrict__ Y0t,
                            const __bf16* __restrict__ Y1t,
                            const float* __restrict__ h,
                            const float* __restrict__ bias,
                            void* __restrict__ outp,
                            int F, int SP) {
    const int i = blockIdx.x * blockDim.x + threadIdx.x;  // (f, node4)
    const int total = F * 2048;
    if (i >= total) return;
    const int f  = i >> 11;
    const int n4 = i & 2047;
    const size_t base = (size_t)f * 8192 + (size_t)n4 * 4;
    const int MN = F * 8192;

    float4 s = *(const float4*)(P + base);
    for (int sp = 1; sp < SP; sp++) {
        float4 v = *(const float4*)(P + (size_t)sp * MN + base);
        s.x += v.x; s.y += v.y; s.z += v.z; s.w += v.w;
    }
    bf16x4 y0 = *(const bf16x4*)(Y0t + base);
    bf16x4 y1 = *(const bf16x4*)(Y1t + base);
    const float h0 = h[0], h1 = h[1], h2 = h[2], bb = bias[f];

    float v[4] = {s.x, s.y, s.z, s.w};
    #pragma unroll
    for (int r = 0; r < 4; r++) {
        float x = h0 * (float)y0[r] + h1 * (float)y1[r] + h2 * v[r] + bb;
        if (RELU) x = fmaxf(x, 0.0f);
        v[r] = x;
    }
    const int node = n4 * 4;
    if (F32OUT) {
        float* O = (float*)outp;
        #pragma unroll
        for (int r = 0; r < 4; r++) O[(size_t)(node + r) * F + f] = v[r];
    } else {
        __bf16* O = (__bf16*)outp;
        #pragma unroll
        for (int r = 0; r < 4; r++) O[(size_t)(node + r) * F + f] = (__bf16)v[r];
    }
}

extern "C" void kernel_launch(void* const* d_in, const int* in_sizes, int n_in,
                              void* d_out, int out_size, void* d_ws, size_t ws_size,
                              hipStream_t stream) {
    const float* S  = (const float*)d_in[0];
    const float* X  = (const float*)d_in[1];
    const float* W1 = (const float*)d_in[2];
    const float* h1 = (const float*)d_in[3];
    const float* b1 = (const float*)d_in[4];
    const float* W2 = (const float*)d_in[5];
    const float* h2 = (const float*)d_in[6];
    const float* b2 = (const float*)d_in[7];
    const float* W3 = (const float*)d_in[8];
    const float* h3 = (const float*)d_in[9];
    const float* b3 = (const float*)d_in[10];
    float* out = (float*)d_out;

    const int Nn = 8192, IN = 512, HID = 128, OUT = 64;

    char* ws = (char*)d_ws;
    size_t off = 0;
    auto carve = [&](size_t bytes) -> void* {
        void* p = ws + off;
        off += (bytes + 255) & ~(size_t)255;
        return p;
    };
    __bf16* Spk = (__bf16*)carve((size_t)Nn * Nn  * 2);   // 134.2 MB packed S
    __bf16* W1t = (__bf16*)carve((size_t)IN  * HID * 2);
    __bf16* W2t = (__bf16*)carve((size_t)HID * HID * 2);
    __bf16* W3t = (__bf16*)carve((size_t)HID * OUT * 2);
    __bf16* Y0t = (__bf16*)carve((size_t)HID * Nn * 2);   // [F][8192]
    __bf16* Y1t = (__bf16*)carve((size_t)HID * Nn * 2);
    __bf16* Act = (__bf16*)carve((size_t)Nn * HID * 2);   // [node][F]
    size_t  base = off;

    // SP=4: P traffic halved vs SP=8; occupancy 2 blocks/CU (== R4/R5 range)
    const size_t per_split = (size_t)HID * Nn * 4;        // 4 MB @F=128
    int SP = 1;
    while (SP < 4 && base + (size_t)(SP * 2) * per_split <= ws_size) SP *= 2;
    float* P = (float*)carve((size_t)SP * per_split);
    const int KCH = Nn / SP;

    // ---- pack S into per-(m,z) stream-order tiles ----
    pack_S<<<dim3(Nn / 64, SP), dim3(256), 0, stream>>>(S, Spk, KCH, SP);
    // ---- fused weight transposes (1 launch) ----
    cvt_transpose3<<<dim3((65536 + 16384 + 8192) / 256), dim3(256), 0, stream>>>(
        W1, W1t, W2, W2t, W3, W3t);

    // S-GEMM: partials P[s][f][node]; grid (128, 1, SP)
    auto sgemm = [&](const __bf16* Bt, int F) {
        if (F == 128)
            sgemm_lds<4><<<dim3(Nn / 64, 1, SP), dim3(256), 0, stream>>>(
                Spk, Bt, P, Nn, KCH, Nn);
        else
            sgemm_lds<2><<<dim3(Nn / 64, 1, SP), dim3(256), 0, stream>>>(
                Spk, Bt, P, Nn, KCH, Nn);
    };
    auto reduceY = [&](__bf16* Y, int F) {
        int t4 = F * 2048;
        reduce_partials<<<dim3((t4 + 255) / 256), dim3(256), 0, stream>>>(
            P, Y, t4, SP, F * Nn);
    };

    // ---- layer 1 ----
    // Y0t = W1t @ X (fp32 B, in-reg convert)  M=128 N=8192 K=512; 256 blocks
    gemm_rd<1, 4, 1, 1><<<dim3(2, Nn / 64, 1), dim3(256), 0, stream>>>(
        W1t, X, Y0t, IN, IN, HID, Nn);
    sgemm(Y0t, HID);                       // P = split-partials of S@Y0
    reduceY(Y1t, HID);                     // Y1t = S@Y0
    sgemm(Y1t, HID);                       // P = split-partials of S@Y1
    combine_out<1, 0><<<dim3(HID * 2048 / 256), dim3(256), 0, stream>>>(
        P, Y0t, Y1t, h1, b1, Act, HID, SP);

    // ---- layer 2 ----
    gemm_rd<1, 4, 1, 0><<<dim3(2, Nn / 64, 1), dim3(256), 0, stream>>>(
        W2t, Act, Y0t, HID, HID, HID, Nn);
    sgemm(Y0t, HID);
    reduceY(Y1t, HID);
    sgemm(Y1t, HID);
    combine_out<1, 0><<<dim3(HID * 2048 / 256), dim3(256), 0, stream>>>(
        P, Y0t, Y1t, h2, b2, Act, HID, SP);

    // ---- layer 3 (F=64, fp32 out, no relu) ----
    gemm_rd<1, 4, 1, 0><<<dim3(1, Nn / 64, 1), dim3(256), 0, stream>>>(
        W3t, Act, Y0t, HID, HID, OUT, Nn);
    sgemm(Y0t, OUT);
    reduceY(Y1t, OUT);
    sgemm(Y1t, OUT);
    combine_out<0, 1><<<dim3(OUT * 2048 / 256), dim3(256), 0, stream>>>(
        P, Y0t, Y1t, h3, b3, out, OUT, SP);

    (void)in_sizes; (void)n_in; (void)out_size;
}

// Round 12
// 712.979 us; speedup vs baseline: 1.0048x; 1.0048x over previous
//
#include <hip/hip_runtime.h>

// ---------------------------------------------------------------------------
// GFGCN round 14: R9 base (best, 696us, SP=8) + non-temporal P traffic.
//
// Theory (fits ALL rounds' data, unlike R3-R13's): readers of freshly
// written workspace (Sb/Spk/Yt/P) pin at ~2-2.5 TB/s; first-touch readers
// and pure writers hit 5-6.7 TB/s -> MALL residency/pollution. P has zero
// reuse; nt stores (write-around) + nt loads (no-allocate) keep the 134-MB
// packed S resident in the 256-MB MALL across all six S-passes.
// Also: fused weight transposes (1 launch), W-GEMM layers 1/2 at 256 blocks.
// pack_S / sgemm pipeline / layouts byte-identical to R9.
// ---------------------------------------------------------------------------

typedef __attribute__((ext_vector_type(4))) float  f32x4;
typedef __attribute__((ext_vector_type(8))) __bf16 bf16x8;
typedef __attribute__((ext_vector_type(4))) __bf16 bf16x4;

__device__ __forceinline__ void gload_lds16(const __bf16* g, __bf16* l) {
    __builtin_amdgcn_global_load_lds(
        (const __attribute__((address_space(1))) void*)g,
        (__attribute__((address_space(3))) void*)l, 16, 0, 0);
}

// ---------------------------------------------------------------------------
// pack_S (verbatim R9): fp32 S -> bf16 packed tiles, tile(m,z) = rows
// [64m,64m+64) x cols[z*KCH,(z+1)*KCH), record(st)=2048 elems: slot t=4*rt+q
// holds S[64m+rt][zKCH+st*32+((q^s(rt))*8)..+8], s(rt)=(rt>>1)&3.
// ---------------------------------------------------------------------------
__global__ __launch_bounds__(256)
void pack_S(const float* __restrict__ S, __bf16* __restrict__ Spk,
            int KCH, int SP) {
    __shared__ __bf16 L[8][1032];
    const int t = threadIdx.x;
    const int m = blockIdx.x, z = blockIdx.y;
    __bf16* tile = Spk + ((size_t)m * SP + z) * ((size_t)64 * KCH);

    const int rl    = t & 7;
    const int cstep = t >> 3;
    const int stl0  = t >> 5;
    const int slot  = t & 31;
    const int rs    = slot >> 2;
    const int q     = slot & 3;

    for (int r0 = 0; r0 < 64; r0 += 8) {
        const int rg_st = r0 + rs;
        const int qq    = q ^ ((rg_st >> 1) & 3);
        for (int c1 = 0; c1 < KCH; c1 += 1024) {
            const float* src = S + (size_t)(m * 64 + r0 + rl) * 8192
                                 + (size_t)z * KCH + c1 + cstep * 32;
            #pragma unroll
            for (int j = 0; j < 4; j++) {
                float4 f0 = *(const float4*)(src + j * 8);
                float4 f1 = *(const float4*)(src + j * 8 + 4);
                bf16x8 v;
                v[0]=(__bf16)f0.x; v[1]=(__bf16)f0.y; v[2]=(__bf16)f0.z; v[3]=(__bf16)f0.w;
                v[4]=(__bf16)f1.x; v[5]=(__bf16)f1.y; v[6]=(__bf16)f1.z; v[7]=(__bf16)f1.w;
                *(bf16x8*)&L[rl][cstep * 32 + j * 8] = v;
            }
            __syncthreads();
            #pragma unroll
            for (int k2 = 0; k2 < 4; k2++) {
                const int stl = stl0 + k2 * 8;
                bf16x8 v = *(const bf16x8*)&L[rs][stl * 32 + qq * 8];
                *(bf16x8*)(tile + (size_t)((c1 >> 5) + stl) * 2048
                                + (size_t)(r0 * 4 + slot) * 8) = v;
            }
            __syncthreads();
        }
    }
}

// ---- all three weight transposes in one launch ----
__global__ void cvt_transpose3(const float* __restrict__ W1, __bf16* __restrict__ W1t,
                               const float* __restrict__ W2, __bf16* __restrict__ W2t,
                               const float* __restrict__ W3, __bf16* __restrict__ W3t) {
    const int i = blockIdx.x * blockDim.x + threadIdx.x;
    if (i < 65536) {                       // W1: 512x128
        int k = i >> 7, m = i & 127;
        W1t[(size_t)m * 512 + k] = (__bf16)W1[i];
    } else if (i < 65536 + 16384) {        // W2: 128x128
        int j = i - 65536;
        int k = j >> 7, m = j & 127;
        W2t[(size_t)m * 128 + k] = (__bf16)W2[j];
    } else if (i < 65536 + 16384 + 8192) { // W3: 128x64
        int j = i - 81920;
        int k = j >> 6, m = j & 63;
        W3t[(size_t)m * 128 + k] = (__bf16)W3[j];
    }
}

// ---------------------------------------------------------------------------
// Register-direct GEMM for W-GEMMs (verbatim R9). BF32=1: B operand fp32.
// ---------------------------------------------------------------------------
template<int MF, int NF, int OUTMODE, int BF32>
__global__ __launch_bounds__(256)
void gemm_rd(const __bf16* __restrict__ A, const void* __restrict__ Bv,
             void* __restrict__ out, int K, int Kchunk, int Mtot, int Ntot)
{
    const int lane = threadIdx.x & 63;
    const int w    = threadIdx.x >> 6;
    const int l15  = lane & 15;
    const int quad = lane >> 4;

    const int m_base = blockIdx.x * (64 * MF) + w * (16 * MF);
    const int n_base = blockIdx.y * (16 * NF);
    const int kstart = blockIdx.z * Kchunk;

    const __bf16* Ap[MF];
    #pragma unroll
    for (int mf = 0; mf < MF; mf++)
        Ap[mf] = A + (size_t)(m_base + mf * 16 + l15) * K + kstart + quad * 8;

    const __bf16* Bp[NF];
    const float*  Bpf[NF];
    #pragma unroll
    for (int nf = 0; nf < NF; nf++) {
        const size_t roff = (size_t)(n_base + nf * 16 + l15) * K + kstart + quad * 8;
        if (BF32) Bpf[nf] = (const float*)Bv + roff;
        else      Bp[nf]  = (const __bf16*)Bv + roff;
    }

    f32x4 acc[MF][NF];
    #pragma unroll
    for (int mf = 0; mf < MF; mf++)
        #pragma unroll
        for (int nf = 0; nf < NF; nf++)
            acc[mf][nf] = (f32x4){0.f, 0.f, 0.f, 0.f};

    #pragma unroll 2
    for (int ks = 0; ks < Kchunk; ks += 32) {
        bf16x8 a[MF], b[NF];
        #pragma unroll
        for (int mf = 0; mf < MF; mf++) a[mf] = *(const bf16x8*)(Ap[mf] + ks);
        #pragma unroll
        for (int nf = 0; nf < NF; nf++) {
            if (BF32) {
                float4 f0 = *(const float4*)(Bpf[nf] + ks);
                float4 f1 = *(const float4*)(Bpf[nf] + ks + 4);
                bf16x8 tt;
                tt[0] = (__bf16)f0.x; tt[1] = (__bf16)f0.y;
                tt[2] = (__bf16)f0.z; tt[3] = (__bf16)f0.w;
                tt[4] = (__bf16)f1.x; tt[5] = (__bf16)f1.y;
                tt[6] = (__bf16)f1.z; tt[7] = (__bf16)f1.w;
                b[nf] = tt;
            } else {
                b[nf] = *(const bf16x8*)(Bp[nf] + ks);
            }
        }
        #pragma unroll
        for (int mf = 0; mf < MF; mf++)
            #pragma unroll
            for (int nf = 0; nf < NF; nf++)
                acc[mf][nf] = __builtin_amdgcn_mfma_f32_16x16x32_bf16(
                    a[mf], b[nf], acc[mf][nf], 0, 0, 0);
    }

    __bf16* O = (__bf16*)out;
    #pragma unroll
    for (int mf = 0; mf < MF; mf++) {
        const int rowb = m_base + mf * 16 + quad * 4;
        #pragma unroll
        for (int nf = 0; nf < NF; nf++) {
            const int col = n_base + nf * 16 + l15;
            #pragma unroll
            for (int r = 0; r < 4; r++)
                O[(size_t)(rowb + r) * Ntot + col] = (__bf16)acc[mf][nf][r];
        }
    }
    (void)Mtot; (void)OUTMODE;
}

// ---------------------------------------------------------------------------
// S-GEMM (R9 structure): 3-deep counted-vmcnt pipeline; A streams
// contiguously from the packed tile. BM=64, BN=32*NFW, BK=32, 2x2 waves.
// ONLY change vs R9: P stores are NON-TEMPORAL (write-around the MALL).
// Output: fp32 partials, t-layout P[z][col][row], rows contiguous (f32x4).
// ---------------------------------------------------------------------------
template<int NFW>
__global__ __launch_bounds__(256)
void sgemm_lds(const __bf16* __restrict__ Spk, const __bf16* __restrict__ Bt,
               float* __restrict__ P, int Kb, int Kchunk, int Mtot)
{
    constexpr int BN = 32 * NFW;               // 128 or 64
    __shared__ __bf16 Asm[3][64 * 32];         // 4KB per buf
    __shared__ __bf16 Bsm[3][BN * 32];         // 8KB (NFW=4) per buf

    const int t    = threadIdx.x;              // 0..255
    const int lane = t & 63;
    const int w    = t >> 6;
    const int wm   = w >> 1;                   // 0..1 (M)
    const int wn   = w & 1;                    // 0..1 (N)
    const int l15  = lane & 15;
    const int quad = lane >> 4;

    const int m_block = blockIdx.x * 64;
    const int kstart  = blockIdx.z * Kchunk;
    const int nst     = Kchunk >> 5;           // BK=32 steps

    // A: contiguous packed tile stream
    const __bf16* gApk = Spk
        + ((size_t)blockIdx.x * gridDim.z + blockIdx.z) * ((size_t)64 * Kchunk);

    // B staging: thread t owns LDS chunk (row=t>>2, q=t&3); source swizzled
    const int rt  = t >> 2;
    const int qs  = (t & 3) ^ ((rt >> 1) & 3);
    const __bf16* gB0 = Bt + (size_t)rt * Kb        + kstart + qs * 8;
    const __bf16* gB1 = Bt + (size_t)(64 + rt) * Kb + kstart + qs * 8;

    f32x4 acc[2][NFW];
    #pragma unroll
    for (int mf = 0; mf < 2; mf++)
        #pragma unroll
        for (int nf = 0; nf < NFW; nf++)
            acc[mf][nf] = (f32x4){0.f, 0.f, 0.f, 0.f};

    auto stage = [&](int buf, int st) {
        gload_lds16(gApk + (size_t)st * 2048 + t * 8, &Asm[buf][t * 8]);
        const int ks = st << 5;
        gload_lds16(gB0 + ks, &Bsm[buf][t * 8]);
        if (NFW == 4)
            gload_lds16(gB1 + ks, &Bsm[buf][2048 + t * 8]);
    };

    // read-side swizzled chunk offsets (k-invariant)
    int aoff[2], boff[NFW];
    #pragma unroll
    for (int mf = 0; mf < 2; mf++) {
        const int ar = wm * 32 + mf * 16 + l15;
        aoff[mf] = ar * 32 + (quad ^ ((ar >> 1) & 3)) * 8;
    }
    #pragma unroll
    for (int nf = 0; nf < NFW; nf++) {
        const int br = wn * 16 * NFW + nf * 16 + l15;
        boff[nf] = br * 32 + (quad ^ ((br >> 1) & 3)) * 8;
    }

    stage(0, 0);
    if (nst > 1) stage(1, 1);
    if (nst > 2) stage(2, 2);

    for (int st = 0; st < nst; ++st) {
        const int rem   = nst - 1 - st;
        const int ahead = rem < 2 ? rem : 2;

        if (ahead == 2) {
            if (NFW == 4) asm volatile("s_waitcnt vmcnt(6)" ::: "memory");
            else          asm volatile("s_waitcnt vmcnt(4)" ::: "memory");
        } else if (ahead == 1) {
            if (NFW == 4) asm volatile("s_waitcnt vmcnt(3)" ::: "memory");
            else          asm volatile("s_waitcnt vmcnt(2)" ::: "memory");
        } else {
            asm volatile("s_waitcnt vmcnt(0)" ::: "memory");
        }
        __builtin_amdgcn_s_barrier();
        asm volatile("" ::: "memory");

        const int buf = st - (st / 3) * 3;     // st % 3
        bf16x8 a[2], b[NFW];
        #pragma unroll
        for (int mf = 0; mf < 2; mf++)
            a[mf] = *(const bf16x8*)&Asm[buf][aoff[mf]];
        #pragma unroll
        for (int nf = 0; nf < NFW; nf++)
            b[nf] = *(const bf16x8*)&Bsm[buf][boff[nf]];

        asm volatile("s_waitcnt lgkmcnt(0)" ::: "memory");
        __builtin_amdgcn_s_barrier();
        asm volatile("" ::: "memory");
        if (st + 3 < nst) stage(buf, st + 3);

        #pragma unroll
        for (int mf = 0; mf < 2; mf++)
            #pragma unroll
            for (int nf = 0; nf < NFW; nf++)
                acc[mf][nf] = __builtin_amdgcn_mfma_f32_16x16x32_bf16(
                    a[mf], b[nf], acc[mf][nf], 0, 0, 0);
    }

    // non-temporal epilogue: write-around the MALL (P has zero reuse)
    float* Pz = P + (size_t)blockIdx.z * Mtot * BN;
    #pragma unroll
    for (int mf = 0; mf < 2; mf++) {
        const int rowb = m_block + wm * 32 + mf * 16 + quad * 4;
        #pragma unroll
        for (int nf = 0; nf < NFW; nf++) {
            const int col = wn * 16 * NFW + nf * 16 + l15;
            __builtin_nontemporal_store(acc[mf][nf],
                (f32x4*)(Pz + (size_t)col * Mtot + rowb));
        }
    }
}

// ---- sum SP split-partials -> bf16 t-layout Y[f][node] (nt P loads) ----
__global__ void reduce_partials(const float* __restrict__ P,
                                __bf16* __restrict__ Y, int total4,
                                int SP, int MN) {
    int i = blockIdx.x * blockDim.x + threadIdx.x;
    if (i >= total4) return;
    size_t base = (size_t)i * 4;
    f32x4 s = __builtin_nontemporal_load((const f32x4*)(P + base));
    for (int sp = 1; sp < SP; sp++) {
        f32x4 v = __builtin_nontemporal_load((const f32x4*)(P + (size_t)sp * MN + base));
        s[0] += v[0]; s[1] += v[1]; s[2] += v[2]; s[3] += v[3];
    }
    bf16x4 o; o[0] = (__bf16)s[0]; o[1] = (__bf16)s[1];
    o[2] = (__bf16)s[2]; o[3] = (__bf16)s[3];
    *(bf16x4*)(Y + base) = o;
}

// ---- combine: out[node][f] = act(h0*Y0 + h1*Y1 + h2*sum(P) + b[f]) ----
template<int RELU, int F32OUT>
__global__ void combine_out(const float* __restrict__ P,
                            const __bf16* __restrict__ Y0t,
                            const __bf16* __restrict__ Y1t,
                            const float* __restrict__ h,
                            const float* __restrict__ bias,
                            void* __restrict__ outp,
                            int F, int SP) {
    const int i = blockIdx.x * blockDim.x + threadIdx.x;  // (f, node4)
    const int total = F * 2048;
    if (i >= total) return;
    const int f  = i >> 11;
    const int n4 = i & 2047;
    const size_t base = (size_t)f * 8192 + (size_t)n4 * 4;
    const int MN = F * 8192;

    f32x4 s = __builtin_nontemporal_load((const f32x4*)(P + base));
    for (int sp = 1; sp < SP; sp++) {
        f32x4 v = __builtin_nontemporal_load((const f32x4*)(P + (size_t)sp * MN + base));
        s[0] += v[0]; s[1] += v[1]; s[2] += v[2]; s[3] += v[3];
    }
    bf16x4 y0 = *(const bf16x4*)(Y0t + base);
    bf16x4 y1 = *(const bf16x4*)(Y1t + base);
    const float h0 = h[0], h1 = h[1], h2 = h[2], bb = bias[f];

    float v[4];
    #pragma unroll
    for (int r = 0; r < 4; r++) {
        float x = h0 * (float)y0[r] + h1 * (float)y1[r] + h2 * s[r] + bb;
        if (RELU) x = fmaxf(x, 0.0f);
        v[r] = x;
    }
    const int node = n4 * 4;
    if (F32OUT) {
        float* O = (float*)outp;
        #pragma unroll
        for (int r = 0; r < 4; r++) O[(size_t)(node + r) * F + f] = v[r];
    } else {
        __bf16* O = (__bf16*)outp;
        #pragma unroll
        for (int r = 0; r < 4; r++) O[(size_t)(node + r) * F + f] = (__bf16)v[r];
    }
}

extern "C" void kernel_launch(void* const* d_in, const int* in_sizes, int n_in,
                              void* d_out, int out_size, void* d_ws, size_t ws_size,
                              hipStream_t stream) {
    const float* S  = (const float*)d_in[0];
    const float* X  = (const float*)d_in[1];
    const float* W1 = (const float*)d_in[2];
    const float* h1 = (const float*)d_in[3];
    const float* b1 = (const float*)d_in[4];
    const float* W2 = (const float*)d_in[5];
    const float* h2 = (const float*)d_in[6];
    const float* b2 = (const float*)d_in[7];
    const float* W3 = (const float*)d_in[8];
    const float* h3 = (const float*)d_in[9];
    const float* b3 = (const float*)d_in[10];
    float* out = (float*)d_out;

    const int Nn = 8192, IN = 512, HID = 128, OUT = 64;

    char* ws = (char*)d_ws;
    size_t off = 0;
    auto carve = [&](size_t bytes) -> void* {
        void* p = ws + off;
        off += (bytes + 255) & ~(size_t)255;
        return p;
    };
    __bf16* Spk = (__bf16*)carve((size_t)Nn * Nn  * 2);   // 134.2 MB packed S
    __bf16* W1t = (__bf16*)carve((size_t)IN  * HID * 2);
    __bf16* W2t = (__bf16*)carve((size_t)HID * HID * 2);
    __bf16* W3t = (__bf16*)carve((size_t)HID * OUT * 2);
    __bf16* Y0t = (__bf16*)carve((size_t)HID * Nn * 2);   // [F][8192]
    __bf16* Y1t = (__bf16*)carve((size_t)HID * Nn * 2);
    __bf16* Act = (__bf16*)carve((size_t)Nn * HID * 2);   // [node][F]
    size_t  base = off;

    // SP=8 (R9 best config)
    const size_t per_split = (size_t)HID * Nn * 4;        // 4 MB @F=128
    int SP = 1;
    while (SP < 8 && base + (size_t)(SP * 2) * per_split <= ws_size) SP *= 2;
    float* P = (float*)carve((size_t)SP * per_split);
    const int KCH = Nn / SP;

    // ---- pack S into per-(m,z) stream-order tiles ----
    pack_S<<<dim3(Nn / 64, SP), dim3(256), 0, stream>>>(S, Spk, KCH, SP);
    // ---- fused weight transposes (1 launch) ----
    cvt_transpose3<<<dim3((65536 + 16384 + 8192) / 256), dim3(256), 0, stream>>>(
        W1, W1t, W2, W2t, W3, W3t);

    // S-GEMM: partials P[s][f][node]; grid (128, 1, SP) = 1024 blocks
    auto sgemm = [&](const __bf16* Bt, int F) {
        if (F == 128)
            sgemm_lds<4><<<dim3(Nn / 64, 1, SP), dim3(256), 0, stream>>>(
                Spk, Bt, P, Nn, KCH, Nn);
        else
            sgemm_lds<2><<<dim3(Nn / 64, 1, SP), dim3(256), 0, stream>>>(
                Spk, Bt, P, Nn, KCH, Nn);
    };
    auto reduceY = [&](__bf16* Y, int F) {
        int t4 = F * 2048;
        reduce_partials<<<dim3((t4 + 255) / 256), dim3(256), 0, stream>>>(
            P, Y, t4, SP, F * Nn);
    };

    // ---- layer 1 ----
    // Y0t = W1t @ X (fp32 B, in-reg convert)  M=128 N=8192 K=512; 256 blocks
    gemm_rd<1, 4, 1, 1><<<dim3(2, Nn / 64, 1), dim3(256), 0, stream>>>(
        W1t, X, Y0t, IN, IN, HID, Nn);
    sgemm(Y0t, HID);                       // P = split-partials of S@Y0
    reduceY(Y1t, HID);                     // Y1t = S@Y0
    sgemm(Y1t, HID);                       // P = split-partials of S@Y1
    combine_out<1, 0><<<dim3(HID * 2048 / 256), dim3(256), 0, stream>>>(
        P, Y0t, Y1t, h1, b1, Act, HID, SP);

    // ---- layer 2 ----
    gemm_rd<1, 4, 1, 0><<<dim3(2, Nn / 64, 1), dim3(256), 0, stream>>>(
        W2t, Act, Y0t, HID, HID, HID, Nn);
    sgemm(Y0t, HID);
    reduceY(Y1t, HID);
    sgemm(Y1t, HID);
    combine_out<1, 0><<<dim3(HID * 2048 / 256), dim3(256), 0, stream>>>(
        P, Y0t, Y1t, h2, b2, Act, HID, SP);

    // ---- layer 3 (F=64, fp32 out, no relu) ----
    gemm_rd<1, 4, 1, 0><<<dim3(1, Nn / 64, 1), dim3(256), 0, stream>>>(
        W3t, Act, Y0t, HID, HID, OUT, Nn);
    sgemm(Y0t, OUT);
    reduceY(Y1t, OUT);
    sgemm(Y1t, OUT);
    combine_out<0, 1><<<dim3(OUT * 2048 / 256), dim3(256), 0, stream>>>(
        P, Y0t, Y1t, h3, b3, out, OUT, SP);

    (void)in_sizes; (void)n_in; (void)out_size;
}

// Round 13
// 696.530 us; speedup vs baseline: 1.0286x; 1.0236x over previous
//
#include <hip/hip_runtime.h>

// ---------------------------------------------------------------------------
// GFGCN round 15: R9 base + 8-wave (512-thread) NFW=4 S-GEMM for 2x TLP.
//
// R6 counter: sgemm Occupancy = 41% (16 waves/CU; LDS 36KB caps 4 blocks/CU
// x 4 waves). All prior latency fixes added ILP, never waves/CU on the
// LDS-staged structure (R3's occupancy probe was register-direct + halved
// tile). Little's law at ~900cy latency and 16 waves/CU reproduces the
// ~2 TB/s band; 32 waves/CU doubles in-flight bytes.
// Change: NFW=4 sgemm -> 512 threads, 2x4 wave grid (wave 32x32, acc 2x2),
// same 36KB 3-stage LDS, same staging maps; per-wave vmcnt 4/2 (A+B waves)
// vs 2/1 (B-only waves). 1024 blocks x 8 waves = chip wave capacity.
// pack_S / W-GEMMs / NFW=2 sgemm / reduce / combine byte-identical to R9.
// ---------------------------------------------------------------------------

typedef __attribute__((ext_vector_type(4))) float  f32x4;
typedef __attribute__((ext_vector_type(8))) __bf16 bf16x8;
typedef __attribute__((ext_vector_type(4))) __bf16 bf16x4;

__device__ __forceinline__ void gload_lds16(const __bf16* g, __bf16* l) {
    __builtin_amdgcn_global_load_lds(
        (const __attribute__((address_space(1))) void*)g,
        (__attribute__((address_space(3))) void*)l, 16, 0, 0);
}

// ---------------------------------------------------------------------------
// pack_S (verbatim R9)
// ---------------------------------------------------------------------------
__global__ __launch_bounds__(256)
void pack_S(const float* __restrict__ S, __bf16* __restrict__ Spk,
            int KCH, int SP) {
    __shared__ __bf16 L[8][1032];
    const int t = threadIdx.x;
    const int m = blockIdx.x, z = blockIdx.y;
    __bf16* tile = Spk + ((size_t)m * SP + z) * ((size_t)64 * KCH);

    const int rl    = t & 7;
    const int cstep = t >> 3;
    const int stl0  = t >> 5;
    const int slot  = t & 31;
    const int rs    = slot >> 2;
    const int q     = slot & 3;

    for (int r0 = 0; r0 < 64; r0 += 8) {
        const int rg_st = r0 + rs;
        const int qq    = q ^ ((rg_st >> 1) & 3);
        for (int c1 = 0; c1 < KCH; c1 += 1024) {
            const float* src = S + (size_t)(m * 64 + r0 + rl) * 8192
                                 + (size_t)z * KCH + c1 + cstep * 32;
            #pragma unroll
            for (int j = 0; j < 4; j++) {
                float4 f0 = *(const float4*)(src + j * 8);
                float4 f1 = *(const float4*)(src + j * 8 + 4);
                bf16x8 v;
                v[0]=(__bf16)f0.x; v[1]=(__bf16)f0.y; v[2]=(__bf16)f0.z; v[3]=(__bf16)f0.w;
                v[4]=(__bf16)f1.x; v[5]=(__bf16)f1.y; v[6]=(__bf16)f1.z; v[7]=(__bf16)f1.w;
                *(bf16x8*)&L[rl][cstep * 32 + j * 8] = v;
            }
            __syncthreads();
            #pragma unroll
            for (int k2 = 0; k2 < 4; k2++) {
                const int stl = stl0 + k2 * 8;
                bf16x8 v = *(const bf16x8*)&L[rs][stl * 32 + qq * 8];
                *(bf16x8*)(tile + (size_t)((c1 >> 5) + stl) * 2048
                                + (size_t)(r0 * 4 + slot) * 8) = v;
            }
            __syncthreads();
        }
    }
}

// ---- fp32 W[K][M] -> bf16 Wt[M][K] (tiny matrices) ----
__global__ void cvt_transpose(const float* __restrict__ W,
                              __bf16* __restrict__ Wt, int Kd, int Md) {
    int i = blockIdx.x * blockDim.x + threadIdx.x;
    if (i < Kd * Md) {
        int k = i / Md, m = i % Md;
        Wt[(size_t)m * Kd + k] = (__bf16)W[i];
    }
}

// ---------------------------------------------------------------------------
// Register-direct GEMM for W-GEMMs (verbatim R9). BF32=1: B operand fp32.
// ---------------------------------------------------------------------------
template<int MF, int NF, int OUTMODE, int BF32>
__global__ __launch_bounds__(256)
void gemm_rd(const __bf16* __restrict__ A, const void* __restrict__ Bv,
             void* __restrict__ out, int K, int Kchunk, int Mtot, int Ntot)
{
    const int lane = threadIdx.x & 63;
    const int w    = threadIdx.x >> 6;
    const int l15  = lane & 15;
    const int quad = lane >> 4;

    const int m_base = blockIdx.x * (64 * MF) + w * (16 * MF);
    const int n_base = blockIdx.y * (16 * NF);
    const int kstart = blockIdx.z * Kchunk;

    const __bf16* Ap[MF];
    #pragma unroll
    for (int mf = 0; mf < MF; mf++)
        Ap[mf] = A + (size_t)(m_base + mf * 16 + l15) * K + kstart + quad * 8;

    const __bf16* Bp[NF];
    const float*  Bpf[NF];
    #pragma unroll
    for (int nf = 0; nf < NF; nf++) {
        const size_t roff = (size_t)(n_base + nf * 16 + l15) * K + kstart + quad * 8;
        if (BF32) Bpf[nf] = (const float*)Bv + roff;
        else      Bp[nf]  = (const __bf16*)Bv + roff;
    }

    f32x4 acc[MF][NF];
    #pragma unroll
    for (int mf = 0; mf < MF; mf++)
        #pragma unroll
        for (int nf = 0; nf < NF; nf++)
            acc[mf][nf] = (f32x4){0.f, 0.f, 0.f, 0.f};

    #pragma unroll 2
    for (int ks = 0; ks < Kchunk; ks += 32) {
        bf16x8 a[MF], b[NF];
        #pragma unroll
        for (int mf = 0; mf < MF; mf++) a[mf] = *(const bf16x8*)(Ap[mf] + ks);
        #pragma unroll
        for (int nf = 0; nf < NF; nf++) {
            if (BF32) {
                float4 f0 = *(const float4*)(Bpf[nf] + ks);
                float4 f1 = *(const float4*)(Bpf[nf] + ks + 4);
                bf16x8 tt;
                tt[0] = (__bf16)f0.x; tt[1] = (__bf16)f0.y;
                tt[2] = (__bf16)f0.z; tt[3] = (__bf16)f0.w;
                tt[4] = (__bf16)f1.x; tt[5] = (__bf16)f1.y;
                tt[6] = (__bf16)f1.z; tt[7] = (__bf16)f1.w;
                b[nf] = tt;
            } else {
                b[nf] = *(const bf16x8*)(Bp[nf] + ks);
            }
        }
        #pragma unroll
        for (int mf = 0; mf < MF; mf++)
            #pragma unroll
            for (int nf = 0; nf < NF; nf++)
                acc[mf][nf] = __builtin_amdgcn_mfma_f32_16x16x32_bf16(
                    a[mf], b[nf], acc[mf][nf], 0, 0, 0);
    }

    __bf16* O = (__bf16*)out;
    #pragma unroll
    for (int mf = 0; mf < MF; mf++) {
        const int rowb = m_base + mf * 16 + quad * 4;
        #pragma unroll
        for (int nf = 0; nf < NF; nf++) {
            const int col = n_base + nf * 16 + l15;
            #pragma unroll
            for (int r = 0; r < 4; r++)
                O[(size_t)(rowb + r) * Ntot + col] = (__bf16)acc[mf][nf][r];
        }
    }
    (void)Mtot; (void)OUTMODE;
}

// ---------------------------------------------------------------------------
// NEW: 8-wave S-GEMM (512 threads), NFW=4 / BN=128 only. Wave grid 2(M)x4(N),
// wave = 32 rows x 32 cols, acc[2][2]. 3-stage LDS (36KB), counted vmcnt.
// A staged by waves 0-3 (packed stream, identity map); B by all 8 waves
// (rt = t>>2 in 0..127, source chunk swizzle s(rt)=(rt>>1)&3).
// Per-wave loads/stage: 2 (w<4) or 1 (w>=4) -> per-wave vmcnt 4/2, 2/1, 0.
// Output: fp32 partials, t-layout P[z][col][row] (verbatim R9 layout).
// ---------------------------------------------------------------------------
__global__ __launch_bounds__(512)
void sgemm_lds8(const __bf16* __restrict__ Spk, const __bf16* __restrict__ Bt,
                float* __restrict__ P, int Kb, int Kchunk, int Mtot)
{
    __shared__ __bf16 Asm[3][64 * 32];          // 4KB per buf
    __shared__ __bf16 Bsm[3][128 * 32];         // 8KB per buf

    const int t    = threadIdx.x;               // 0..511
    const int lane = t & 63;
    const int w    = t >> 6;                    // wave 0..7
    const int wm   = w >> 2;                    // 0..1 (M)
    const int wn   = w & 3;                     // 0..3 (N)
    const int l15  = lane & 15;
    const int quad = lane >> 4;

    const int m_block = blockIdx.x * 64;
    const int kstart  = blockIdx.z * Kchunk;
    const int nst     = Kchunk >> 5;            // BK=32 steps

    // A: contiguous packed tile stream (records of 2048 elems)
    const __bf16* gApk = Spk
        + ((size_t)blockIdx.x * gridDim.z + blockIdx.z) * ((size_t)64 * Kchunk);

    // B staging: thread t owns LDS chunk (row rt = t>>2 in 0..127, q = t&3)
    const int rt  = t >> 2;
    const int qs  = (t & 3) ^ ((rt >> 1) & 3);
    const __bf16* gB = Bt + (size_t)rt * Kb + kstart + qs * 8;

    f32x4 acc[2][2];
    #pragma unroll
    for (int mf = 0; mf < 2; mf++)
        #pragma unroll
        for (int nf = 0; nf < 2; nf++)
            acc[mf][nf] = (f32x4){0.f, 0.f, 0.f, 0.f};

    auto stage = [&](int buf, int st) {
        if (t < 256)   // waves 0-3: A tile (4KB)
            gload_lds16(gApk + (size_t)st * 2048 + t * 8, &Asm[buf][t * 8]);
        // all 8 waves: B tile (8KB)
        gload_lds16(gB + (st << 5), &Bsm[buf][t * 8]);
    };

    // read-side swizzled chunk offsets (k-invariant)
    int aoff[2], boff[2];
    #pragma unroll
    for (int mf = 0; mf < 2; mf++) {
        const int ar = wm * 32 + mf * 16 + l15;
        aoff[mf] = ar * 32 + (quad ^ ((ar >> 1) & 3)) * 8;
    }
    #pragma unroll
    for (int nf = 0; nf < 2; nf++) {
        const int br = wn * 32 + nf * 16 + l15;
        boff[nf] = br * 32 + (quad ^ ((br >> 1) & 3)) * 8;
    }

    stage(0, 0);
    if (nst > 1) stage(1, 1);
    if (nst > 2) stage(2, 2);

    for (int st = 0; st < nst; ++st) {
        const int rem   = nst - 1 - st;
        const int ahead = rem < 2 ? rem : 2;

        if (w < 4) {          // 2 loads/stage
            if      (ahead == 2) asm volatile("s_waitcnt vmcnt(4)" ::: "memory");
            else if (ahead == 1) asm volatile("s_waitcnt vmcnt(2)" ::: "memory");
            else                 asm volatile("s_waitcnt vmcnt(0)" ::: "memory");
        } else {              // 1 load/stage
            if      (ahead == 2) asm volatile("s_waitcnt vmcnt(2)" ::: "memory");
            else if (ahead == 1) asm volatile("s_waitcnt vmcnt(1)" ::: "memory");
            else                 asm volatile("s_waitcnt vmcnt(0)" ::: "memory");
        }
        __builtin_amdgcn_s_barrier();           // stage st resident for all
        asm volatile("" ::: "memory");

        const int buf = st - (st / 3) * 3;      // st % 3
        bf16x8 a[2], b[2];
        #pragma unroll
        for (int mf = 0; mf < 2; mf++)
            a[mf] = *(const bf16x8*)&Asm[buf][aoff[mf]];
        #pragma unroll
        for (int nf = 0; nf < 2; nf++)
            b[nf] = *(const bf16x8*)&Bsm[buf][boff[nf]];

        asm volatile("s_waitcnt lgkmcnt(0)" ::: "memory");
        __builtin_amdgcn_s_barrier();           // all waves done with slot
        asm volatile("" ::: "memory");
        if (st + 3 < nst) stage(buf, st + 3);

        #pragma unroll
        for (int mf = 0; mf < 2; mf++)
            #pragma unroll
            for (int nf = 0; nf < 2; nf++)
                acc[mf][nf] = __builtin_amdgcn_mfma_f32_16x16x32_bf16(
                    a[mf], b[nf], acc[mf][nf], 0, 0, 0);
    }

    float* Pz = P + (size_t)blockIdx.z * Mtot * 128;
    #pragma unroll
    for (int mf = 0; mf < 2; mf++) {
        const int rowb = m_block + wm * 32 + mf * 16 + quad * 4;
        #pragma unroll
        for (int nf = 0; nf < 2; nf++) {
            const int col = wn * 32 + nf * 16 + l15;
            *(f32x4*)(Pz + (size_t)col * Mtot + rowb) = acc[mf][nf];
        }
    }
}

// ---------------------------------------------------------------------------
// S-GEMM (verbatim R9, used for NFW=2 / layer 3): 3-deep counted-vmcnt,
// 256 threads, 2x2 waves.
// ---------------------------------------------------------------------------
template<int NFW>
__global__ __launch_bounds__(256)
void sgemm_lds(const __bf16* __restrict__ Spk, const __bf16* __restrict__ Bt,
               float* __restrict__ P, int Kb, int Kchunk, int Mtot)
{
    constexpr int BN = 32 * NFW;
    __shared__ __bf16 Asm[3][64 * 32];
    __shared__ __bf16 Bsm[3][BN * 32];

    const int t    = threadIdx.x;
    const int lane = t & 63;
    const int w    = t >> 6;
    const int wm   = w >> 1;
    const int wn   = w & 1;
    const int l15  = lane & 15;
    const int quad = lane >> 4;

    const int m_block = blockIdx.x * 64;
    const int kstart  = blockIdx.z * Kchunk;
    const int nst     = Kchunk >> 5;

    const __bf16* gApk = Spk
        + ((size_t)blockIdx.x * gridDim.z + blockIdx.z) * ((size_t)64 * Kchunk);

    const int rt  = t >> 2;
    const int qs  = (t & 3) ^ ((rt >> 1) & 3);
    const __bf16* gB0 = Bt + (size_t)rt * Kb        + kstart + qs * 8;
    const __bf16* gB1 = Bt + (size_t)(64 + rt) * Kb + kstart + qs * 8;

    f32x4 acc[2][NFW];
    #pragma unroll
    for (int mf = 0; mf < 2; mf++)
        #pragma unroll
        for (int nf = 0; nf < NFW; nf++)
            acc[mf][nf] = (f32x4){0.f, 0.f, 0.f, 0.f};

    auto stage = [&](int buf, int st) {
        gload_lds16(gApk + (size_t)st * 2048 + t * 8, &Asm[buf][t * 8]);
        const int ks = st << 5;
        gload_lds16(gB0 + ks, &Bsm[buf][t * 8]);
        if (NFW == 4)
            gload_lds16(gB1 + ks, &Bsm[buf][2048 + t * 8]);
    };

    int aoff[2], boff[NFW];
    #pragma unroll
    for (int mf = 0; mf < 2; mf++) {
        const int ar = wm * 32 + mf * 16 + l15;
        aoff[mf] = ar * 32 + (quad ^ ((ar >> 1) & 3)) * 8;
    }
    #pragma unroll
    for (int nf = 0; nf < NFW; nf++) {
        const int br = wn * 16 * NFW + nf * 16 + l15;
        boff[nf] = br * 32 + (quad ^ ((br >> 1) & 3)) * 8;
    }

    stage(0, 0);
    if (nst > 1) stage(1, 1);
    if (nst > 2) stage(2, 2);

    for (int st = 0; st < nst; ++st) {
        const int rem   = nst - 1 - st;
        const int ahead = rem < 2 ? rem : 2;

        if (ahead == 2) {
            if (NFW == 4) asm volatile("s_waitcnt vmcnt(6)" ::: "memory");
            else          asm volatile("s_waitcnt vmcnt(4)" ::: "memory");
        } else if (ahead == 1) {
            if (NFW == 4) asm volatile("s_waitcnt vmcnt(3)" ::: "memory");
            else          asm volatile("s_waitcnt vmcnt(2)" ::: "memory");
        } else {
            asm volatile("s_waitcnt vmcnt(0)" ::: "memory");
        }
        __builtin_amdgcn_s_barrier();
        asm volatile("" ::: "memory");

        const int buf = st - (st / 3) * 3;
        bf16x8 a[2], b[NFW];
        #pragma unroll
        for (int mf = 0; mf < 2; mf++)
            a[mf] = *(const bf16x8*)&Asm[buf][aoff[mf]];
        #pragma unroll
        for (int nf = 0; nf < NFW; nf++)
            b[nf] = *(const bf16x8*)&Bsm[buf][boff[nf]];

        asm volatile("s_waitcnt lgkmcnt(0)" ::: "memory");
        __builtin_amdgcn_s_barrier();
        asm volatile("" ::: "memory");
        if (st + 3 < nst) stage(buf, st + 3);

        #pragma unroll
        for (int mf = 0; mf < 2; mf++)
            #pragma unroll
            for (int nf = 0; nf < NFW; nf++)
                acc[mf][nf] = __builtin_amdgcn_mfma_f32_16x16x32_bf16(
                    a[mf], b[nf], acc[mf][nf], 0, 0, 0);
    }

    float* Pz = P + (size_t)blockIdx.z * Mtot * BN;
    #pragma unroll
    for (int mf = 0; mf < 2; mf++) {
        const int rowb = m_block + wm * 32 + mf * 16 + quad * 4;
        #pragma unroll
        for (int nf = 0; nf < NFW; nf++) {
            const int col = wn * 16 * NFW + nf * 16 + l15;
            *(f32x4*)(Pz + (size_t)col * Mtot + rowb) = acc[mf][nf];
        }
    }
}

// ---- sum SP split-partials -> bf16 t-layout Y[f][node] ----
__global__ void reduce_partials(const float* __restrict__ P,
                                __bf16* __restrict__ Y, int total4,
                                int SP, int MN) {
    int i = blockIdx.x * blockDim.x + threadIdx.x;
    if (i >= total4) return;
    size_t base = (size_t)i * 4;
    float4 s = *(const float4*)(P + base);
    for (int sp = 1; sp < SP; sp++) {
        float4 v = *(const float4*)(P + (size_t)sp * MN + base);
        s.x += v.x; s.y += v.y; s.z += v.z; s.w += v.w;
    }
    bf16x4 o; o[0] = (__bf16)s.x; o[1] = (__bf16)s.y;
    o[2] = (__bf16)s.z; o[3] = (__bf16)s.w;
    *(bf16x4*)(Y + base) = o;
}

// ---- combine: out[node][f] = act(h0*Y0 + h1*Y1 + h2*sum(P) + b[f]) ----
template<int RELU, int F32OUT>
__global__ void combine_out(const float* __restrict__ P,
                            const __bf16* __restrict__ Y0t,
                            const __bf16* __restrict__ Y1t,
                            const float* __restrict__ h,
                            const float* __restrict__ bias,
                            void* __restrict__ outp,
                            int F, int SP) {
    const int i = blockIdx.x * blockDim.x + threadIdx.x;  // (f, node4)
    const int total = F * 2048;
    if (i >= total) return;
    const int f  = i >> 11;
    const int n4 = i & 2047;
    const size_t base = (size_t)f * 8192 + (size_t)n4 * 4;
    const int MN = F * 8192;

    float4 s = *(const float4*)(P + base);
    for (int sp = 1; sp < SP; sp++) {
        float4 v = *(const float4*)(P + (size_t)sp * MN + base);
        s.x += v.x; s.y += v.y; s.z += v.z; s.w += v.w;
    }
    bf16x4 y0 = *(const bf16x4*)(Y0t + base);
    bf16x4 y1 = *(const bf16x4*)(Y1t + base);
    const float h0 = h[0], h1 = h[1], h2 = h[2], bb = bias[f];

    float v[4] = {s.x, s.y, s.z, s.w};
    #pragma unroll
    for (int r = 0; r < 4; r++) {
        float x = h0 * (float)y0[r] + h1 * (float)y1[r] + h2 * v[r] + bb;
        if (RELU) x = fmaxf(x, 0.0f);
        v[r] = x;
    }
    const int node = n4 * 4;
    if (F32OUT) {
        float* O = (float*)outp;
        #pragma unroll
        for (int r = 0; r < 4; r++) O[(size_t)(node + r) * F + f] = v[r];
    } else {
        __bf16* O = (__bf16*)outp;
        #pragma unroll
        for (int r = 0; r < 4; r++) O[(size_t)(node + r) * F + f] = (__bf16)v[r];
    }
}

extern "C" void kernel_launch(void* const* d_in, const int* in_sizes, int n_in,
                              void* d_out, int out_size, void* d_ws, size_t ws_size,
                              hipStream_t stream) {
    const float* S  = (const float*)d_in[0];
    const float* X  = (const float*)d_in[1];
    const float* W1 = (const float*)d_in[2];
    const float* h1 = (const float*)d_in[3];
    const float* b1 = (const float*)d_in[4];
    const float* W2 = (const float*)d_in[5];
    const float* h2 = (const float*)d_in[6];
    const float* b2 = (const float*)d_in[7];
    const float* W3 = (const float*)d_in[8];
    const float* h3 = (const float*)d_in[9];
    const float* b3 = (const float*)d_in[10];
    float* out = (float*)d_out;

    const int Nn = 8192, IN = 512, HID = 128, OUT = 64;

    char* ws = (char*)d_ws;
    size_t off = 0;
    auto carve = [&](size_t bytes) -> void* {
        void* p = ws + off;
        off += (bytes + 255) & ~(size_t)255;
        return p;
    };
    __bf16* Spk = (__bf16*)carve((size_t)Nn * Nn  * 2);   // 134.2 MB packed S
    __bf16* W1t = (__bf16*)carve((size_t)IN  * HID * 2);
    __bf16* W2t = (__bf16*)carve((size_t)HID * HID * 2);
    __bf16* W3t = (__bf16*)carve((size_t)HID * OUT * 2);
    __bf16* Y0t = (__bf16*)carve((size_t)HID * Nn * 2);   // [F][8192]
    __bf16* Y1t = (__bf16*)carve((size_t)HID * Nn * 2);
    __bf16* Act = (__bf16*)carve((size_t)Nn * HID * 2);   // [node][F]
    size_t  base = off;

    // SP=8 (R9 best config)
    const size_t per_split = (size_t)HID * Nn * 4;        // 4 MB @F=128
    int SP = 1;
    while (SP < 8 && base + (size_t)(SP * 2) * per_split <= ws_size) SP *= 2;
    float* P = (float*)carve((size_t)SP * per_split);
    const int KCH = Nn / SP;

    // ---- pack S into per-(m,z) stream-order tiles ----
    pack_S<<<dim3(Nn / 64, SP), dim3(256), 0, stream>>>(S, Spk, KCH, SP);
    // ---- tiny weight transposes ----
    cvt_transpose<<<dim3((IN * HID + 255) / 256), dim3(256), 0, stream>>>(W1, W1t, IN, HID);
    cvt_transpose<<<dim3((HID * HID + 255) / 256), dim3(256), 0, stream>>>(W2, W2t, HID, HID);
    cvt_transpose<<<dim3((HID * OUT + 255) / 256), dim3(256), 0, stream>>>(W3, W3t, HID, OUT);

    // S-GEMM: partials P[s][f][node]; grid (128, 1, SP) = 1024 blocks
    auto sgemm = [&](const __bf16* Bt, int F) {
        if (F == 128)
            sgemm_lds8<<<dim3(Nn / 64, 1, SP), dim3(512), 0, stream>>>(
                Spk, Bt, P, Nn, KCH, Nn);
        else
            sgemm_lds<2><<<dim3(Nn / 64, 1, SP), dim3(256), 0, stream>>>(
                Spk, Bt, P, Nn, KCH, Nn);
    };
    auto reduceY = [&](__bf16* Y, int F) {
        int t4 = F * 2048;
        reduce_partials<<<dim3((t4 + 255) / 256), dim3(256), 0, stream>>>(
            P, Y, t4, SP, F * Nn);
    };

    // ---- layer 1 ----
    gemm_rd<2, 4, 1, 1><<<dim3(1, Nn / 64, 1), dim3(256), 0, stream>>>(
        W1t, X, Y0t, IN, IN, HID, Nn);
    sgemm(Y0t, HID);                       // P = split-partials of S@Y0
    reduceY(Y1t, HID);                     // Y1t = S@Y0
    sgemm(Y1t, HID);                       // P = split-partials of S@Y1
    combine_out<1, 0><<<dim3(HID * 2048 / 256), dim3(256), 0, stream>>>(
        P, Y0t, Y1t, h1, b1, Act, HID, SP);

    // ---- layer 2 ----
    gemm_rd<2, 4, 1, 0><<<dim3(1, Nn / 64, 1), dim3(256), 0, stream>>>(
        W2t, Act, Y0t, HID, HID, HID, Nn);
    sgemm(Y0t, HID);
    reduceY(Y1t, HID);
    sgemm(Y1t, HID);
    combine_out<1, 0><<<dim3(HID * 2048 / 256), dim3(256), 0, stream>>>(
        P, Y0t, Y1t, h2, b2, Act, HID, SP);

    // ---- layer 3 (F=64, fp32 out, no relu) ----
    gemm_rd<1, 4, 1, 0><<<dim3(1, Nn / 64, 1), dim3(256), 0, stream>>>(
        W3t, Act, Y0t, HID, HID, OUT, Nn);
    sgemm(Y0t, OUT);
    reduceY(Y1t, OUT);
    sgemm(Y1t, OUT);
    combine_out<0, 1><<<dim3(OUT * 2048 / 256), dim3(256), 0, stream>>>(
        P, Y0t, Y1t, h3, b3, out, OUT, SP);

    (void)in_sizes; (void)n_in; (void)out_size;
}

// Round 14
// 694.839 us; speedup vs baseline: 1.0311x; 1.0024x over previous
//
#include <hip/hip_runtime.h>

// ---------------------------------------------------------------------------
// GFGCN FINAL (= round 9 verbatim, session best: 696.1us; confirmed 696.5
// by R15's equal-performing variant). Panel-packed S -> sequential S-GEMM
// streaming, 3-deep counted-vmcnt pipeline, SP=8 split-K.
//
// Session verdict after 14 falsified theories (occupancy, LDS conflicts,
// barrier drain, DRAM stride, contiguity, gang-lockstep, split-K bytes,
// staging mechanism, write granularity, MALL hints, TLP): the S-GEMM access
// class pins at ~2-2.5 TB/s effective with MfmaUtil 4% / VALU 12% / HBM
// 25-30% -- a local minimum invariant to every HIP-source-level lever.
// Arithmetic floor ~300us is unreachable without a mechanism explaining
// that band; locking the best verified artifact.
// ---------------------------------------------------------------------------

typedef __attribute__((ext_vector_type(4))) float  f32x4;
typedef __attribute__((ext_vector_type(8))) __bf16 bf16x8;
typedef __attribute__((ext_vector_type(4))) __bf16 bf16x4;

__device__ __forceinline__ void gload_lds16(const __bf16* g, __bf16* l) {
    __builtin_amdgcn_global_load_lds(
        (const __attribute__((address_space(1))) void*)g,
        (__attribute__((address_space(3))) void*)l, 16, 0, 0);
}

// ---------------------------------------------------------------------------
// pack_S: fp32 S[8192][8192] -> bf16 Spk, tile(m,z) = rows[64m,64m+64) x
// cols[z*KCH,(z+1)*KCH), layout: [st][slot t 0..255][8 elems], where slot
// t=4*rt+q holds S[64m+rt][z*KCH+st*32+((q^s(rt))*8)..+8], s(rt)=(rt>>1)&3.
// ---------------------------------------------------------------------------
__global__ __launch_bounds__(256)
void pack_S(const float* __restrict__ S, __bf16* __restrict__ Spk,
            int KCH, int SP) {
    __shared__ __bf16 L[8][1032];   // 8 rows x 1024 cols (+8 pad), 16.5 KB
    const int t = threadIdx.x;
    const int m = blockIdx.x, z = blockIdx.y;
    __bf16* tile = Spk + ((size_t)m * SP + z) * ((size_t)64 * KCH);

    const int rl    = t & 7;        // local row (load phase)
    const int cstep = t >> 3;       // 32-elem col chunk (0..31)
    const int stl0  = t >> 5;       // step sub-index (store phase)
    const int slot  = t & 31;       // slot within the 8-row stripe
    const int rs    = slot >> 2;    // local row (store phase)
    const int q     = slot & 3;

    for (int r0 = 0; r0 < 64; r0 += 8) {
        const int rg_st = r0 + rs;
        const int qq    = q ^ ((rg_st >> 1) & 3);
        for (int c1 = 0; c1 < KCH; c1 += 1024) {
            // ---- load 8 rows x 1024 fp32 (4KB/row contiguous), cvt->LDS ----
            const float* src = S + (size_t)(m * 64 + r0 + rl) * 8192
                                 + (size_t)z * KCH + c1 + cstep * 32;
            #pragma unroll
            for (int j = 0; j < 4; j++) {
                float4 f0 = *(const float4*)(src + j * 8);
                float4 f1 = *(const float4*)(src + j * 8 + 4);
                bf16x8 v;
                v[0]=(__bf16)f0.x; v[1]=(__bf16)f0.y; v[2]=(__bf16)f0.z; v[3]=(__bf16)f0.w;
                v[4]=(__bf16)f1.x; v[5]=(__bf16)f1.y; v[6]=(__bf16)f1.z; v[7]=(__bf16)f1.w;
                *(bf16x8*)&L[rl][cstep * 32 + j * 8] = v;
            }
            __syncthreads();
            // ---- store in consumption order (512B per step-stripe) ----
            #pragma unroll
            for (int k2 = 0; k2 < 4; k2++) {
                const int stl = stl0 + k2 * 8;          // 0..31
                bf16x8 v = *(const bf16x8*)&L[rs][stl * 32 + qq * 8];
                *(bf16x8*)(tile + (size_t)((c1 >> 5) + stl) * 2048
                                + (size_t)(r0 * 4 + slot) * 8) = v;
            }
            __syncthreads();
        }
    }
}

// ---- fp32 W[K][M] -> bf16 Wt[M][K] (tiny matrices) ----
__global__ void cvt_transpose(const float* __restrict__ W,
                              __bf16* __restrict__ Wt, int Kd, int Md) {
    int i = blockIdx.x * blockDim.x + threadIdx.x;
    if (i < Kd * Md) {
        int k = i / Md, m = i % Md;
        Wt[(size_t)m * Kd + k] = (__bf16)W[i];
    }
}

// ---------------------------------------------------------------------------
// Register-direct GEMM for W-GEMMs (small K). BF32=1: B operand fp32,
// in-reg convert (removes the X convert pass).
// ---------------------------------------------------------------------------
template<int MF, int NF, int OUTMODE, int BF32>
__global__ __launch_bounds__(256)
void gemm_rd(const __bf16* __restrict__ A, const void* __restrict__ Bv,
             void* __restrict__ out, int K, int Kchunk, int Mtot, int Ntot)
{
    const int lane = threadIdx.x & 63;
    const int w    = threadIdx.x >> 6;
    const int l15  = lane & 15;
    const int quad = lane >> 4;

    const int m_base = blockIdx.x * (64 * MF) + w * (16 * MF);
    const int n_base = blockIdx.y * (16 * NF);
    const int kstart = blockIdx.z * Kchunk;

    const __bf16* Ap[MF];
    #pragma unroll
    for (int mf = 0; mf < MF; mf++)
        Ap[mf] = A + (size_t)(m_base + mf * 16 + l15) * K + kstart + quad * 8;

    const __bf16* Bp[NF];
    const float*  Bpf[NF];
    #pragma unroll
    for (int nf = 0; nf < NF; nf++) {
        const size_t roff = (size_t)(n_base + nf * 16 + l15) * K + kstart + quad * 8;
        if (BF32) Bpf[nf] = (const float*)Bv + roff;
        else      Bp[nf]  = (const __bf16*)Bv + roff;
    }

    f32x4 acc[MF][NF];
    #pragma unroll
    for (int mf = 0; mf < MF; mf++)
        #pragma unroll
        for (int nf = 0; nf < NF; nf++)
            acc[mf][nf] = (f32x4){0.f, 0.f, 0.f, 0.f};

    #pragma unroll 2
    for (int ks = 0; ks < Kchunk; ks += 32) {
        bf16x8 a[MF], b[NF];
        #pragma unroll
        for (int mf = 0; mf < MF; mf++) a[mf] = *(const bf16x8*)(Ap[mf] + ks);
        #pragma unroll
        for (int nf = 0; nf < NF; nf++) {
            if (BF32) {
                float4 f0 = *(const float4*)(Bpf[nf] + ks);
                float4 f1 = *(const float4*)(Bpf[nf] + ks + 4);
                bf16x8 tt;
                tt[0] = (__bf16)f0.x; tt[1] = (__bf16)f0.y;
                tt[2] = (__bf16)f0.z; tt[3] = (__bf16)f0.w;
                tt[4] = (__bf16)f1.x; tt[5] = (__bf16)f1.y;
                tt[6] = (__bf16)f1.z; tt[7] = (__bf16)f1.w;
                b[nf] = tt;
            } else {
                b[nf] = *(const bf16x8*)(Bp[nf] + ks);
            }
        }
        #pragma unroll
        for (int mf = 0; mf < MF; mf++)
            #pragma unroll
            for (int nf = 0; nf < NF; nf++)
                acc[mf][nf] = __builtin_amdgcn_mfma_f32_16x16x32_bf16(
                    a[mf], b[nf], acc[mf][nf], 0, 0, 0);
    }

    if (OUTMODE == 0) {
        float* P = (float*)out + (size_t)blockIdx.z * Mtot * Ntot;
        #pragma unroll
        for (int mf = 0; mf < MF; mf++) {
            const int rowb = m_base + mf * 16 + quad * 4;
            #pragma unroll
            for (int nf = 0; nf < NF; nf++) {
                const int col = n_base + nf * 16 + l15;
                *(f32x4*)(P + (size_t)col * Mtot + rowb) = acc[mf][nf];
            }
        }
    } else {
        __bf16* O = (__bf16*)out;
        #pragma unroll
        for (int mf = 0; mf < MF; mf++) {
            const int rowb = m_base + mf * 16 + quad * 4;
            #pragma unroll
            for (int nf = 0; nf < NF; nf++) {
                const int col = n_base + nf * 16 + l15;
                #pragma unroll
                for (int r = 0; r < 4; r++)
                    O[(size_t)(rowb + r) * Ntot + col] = (__bf16)acc[mf][nf][r];
            }
        }
    }
}

// ---------------------------------------------------------------------------
// S-GEMM: 3-deep counted-vmcnt pipeline; A streams CONTIGUOUSLY from the
// packed tile (m=blockIdx.x, z=blockIdx.z).
// BM=64, BN=32*NFW, BK=32, 2x2 waves, LDS 36KB -> 4 blocks/CU, grid 1024.
// B (Yt, row stride Kb=8192) staged via swizzled-source gload_lds.
// Output: fp32 partials, t-layout P[z][col][row], rows contiguous (f32x4).
// ---------------------------------------------------------------------------
template<int NFW>
__global__ __launch_bounds__(256)
void sgemm_lds(const __bf16* __restrict__ Spk, const __bf16* __restrict__ Bt,
               float* __restrict__ P, int Kb, int Kchunk, int Mtot)
{
    constexpr int BN = 32 * NFW;               // 128 or 64
    __shared__ __bf16 Asm[3][64 * 32];         // 4KB per buf
    __shared__ __bf16 Bsm[3][BN * 32];         // 8KB (NFW=4) per buf

    const int t    = threadIdx.x;              // 0..255
    const int lane = t & 63;
    const int w    = t >> 6;
    const int wm   = w >> 1;                   // 0..1 (M)
    const int wn   = w & 1;                    // 0..1 (N)
    const int l15  = lane & 15;
    const int quad = lane >> 4;

    const int m_block = blockIdx.x * 64;
    const int kstart  = blockIdx.z * Kchunk;
    const int nst     = Kchunk >> 5;           // BK=32 steps

    // A: contiguous packed tile stream
    const __bf16* gApk = Spk
        + ((size_t)blockIdx.x * gridDim.z + blockIdx.z) * ((size_t)64 * Kchunk);

    // B staging: thread t owns LDS chunk (row=t>>2, q=t&3); source swizzled
    const int rt  = t >> 2;
    const int qs  = (t & 3) ^ ((rt >> 1) & 3);
    const __bf16* gB0 = Bt + (size_t)rt * Kb        + kstart + qs * 8;
    const __bf16* gB1 = Bt + (size_t)(64 + rt) * Kb + kstart + qs * 8;

    f32x4 acc[2][NFW];
    #pragma unroll
    for (int mf = 0; mf < 2; mf++)
        #pragma unroll
        for (int nf = 0; nf < NFW; nf++)
            acc[mf][nf] = (f32x4){0.f, 0.f, 0.f, 0.f};

    auto stage = [&](int buf, int st) {
        gload_lds16(gApk + (size_t)st * 2048 + t * 8, &Asm[buf][t * 8]);
        const int ks = st << 5;
        gload_lds16(gB0 + ks, &Bsm[buf][t * 8]);
        if (NFW == 4)
            gload_lds16(gB1 + ks, &Bsm[buf][2048 + t * 8]);
    };

    // read-side swizzled chunk offsets (k-invariant)
    int aoff[2], boff[NFW];
    #pragma unroll
    for (int mf = 0; mf < 2; mf++) {
        const int ar = wm * 32 + mf * 16 + l15;
        aoff[mf] = ar * 32 + (quad ^ ((ar >> 1) & 3)) * 8;
    }
    #pragma unroll
    for (int nf = 0; nf < NFW; nf++) {
        const int br = wn * 16 * NFW + nf * 16 + l15;
        boff[nf] = br * 32 + (quad ^ ((br >> 1) & 3)) * 8;
    }

    stage(0, 0);
    if (nst > 1) stage(1, 1);
    if (nst > 2) stage(2, 2);

    for (int st = 0; st < nst; ++st) {
        const int rem   = nst - 1 - st;
        const int ahead = rem < 2 ? rem : 2;

        if (ahead == 2) {
            if (NFW == 4) asm volatile("s_waitcnt vmcnt(6)" ::: "memory");
            else          asm volatile("s_waitcnt vmcnt(4)" ::: "memory");
        } else if (ahead == 1) {
            if (NFW == 4) asm volatile("s_waitcnt vmcnt(3)" ::: "memory");
            else          asm volatile("s_waitcnt vmcnt(2)" ::: "memory");
        } else {
            asm volatile("s_waitcnt vmcnt(0)" ::: "memory");
        }
        __builtin_amdgcn_s_barrier();
        asm volatile("" ::: "memory");

        const int buf = st - (st / 3) * 3;     // st % 3
        bf16x8 a[2], b[NFW];
        #pragma unroll
        for (int mf = 0; mf < 2; mf++)
            a[mf] = *(const bf16x8*)&Asm[buf][aoff[mf]];
        #pragma unroll
        for (int nf = 0; nf < NFW; nf++)
            b[nf] = *(const bf16x8*)&Bsm[buf][boff[nf]];

        asm volatile("s_waitcnt lgkmcnt(0)" ::: "memory");
        __builtin_amdgcn_s_barrier();
        asm volatile("" ::: "memory");
        if (st + 3 < nst) stage(buf, st + 3);

        #pragma unroll
        for (int mf = 0; mf < 2; mf++)
            #pragma unroll
            for (int nf = 0; nf < NFW; nf++)
                acc[mf][nf] = __builtin_amdgcn_mfma_f32_16x16x32_bf16(
                    a[mf], b[nf], acc[mf][nf], 0, 0, 0);
    }

    float* Pz = P + (size_t)blockIdx.z * Mtot * BN;
    #pragma unroll
    for (int mf = 0; mf < 2; mf++) {
        const int rowb = m_block + wm * 32 + mf * 16 + quad * 4;
        #pragma unroll
        for (int nf = 0; nf < NFW; nf++) {
            const int col = wn * 16 * NFW + nf * 16 + l15;
            *(f32x4*)(Pz + (size_t)col * Mtot + rowb) = acc[mf][nf];
        }
    }
}

// ---- sum SP split-partials -> bf16 t-layout Y[f][node] ----
__global__ void reduce_partials(const float* __restrict__ P,
                                __bf16* __restrict__ Y, int total4,
                                int SP, int MN) {
    int i = blockIdx.x * blockDim.x + threadIdx.x;
    if (i >= total4) return;
    size_t base = (size_t)i * 4;
    float4 s = *(const float4*)(P + base);
    for (int sp = 1; sp < SP; sp++) {
        float4 v = *(const float4*)(P + (size_t)sp * MN + base);
        s.x += v.x; s.y += v.y; s.z += v.z; s.w += v.w;
    }
    bf16x4 o; o[0] = (__bf16)s.x; o[1] = (__bf16)s.y;
    o[2] = (__bf16)s.z; o[3] = (__bf16)s.w;
    *(bf16x4*)(Y + base) = o;
}

// ---- combine: out[node][f] = act(h0*Y0 + h1*Y1 + h2*sum(P) + b[f]) ----
template<int RELU, int F32OUT>
__global__ void combine_out(const float* __restrict__ P,
                            const __bf16* __restrict__ Y0t,
                            const __bf16* __restrict__ Y1t,
                            const float* __restrict__ h,
                            const float* __restrict__ bias,
                            void* __restrict__ outp,
                            int F, int SP) {
    const int i = blockIdx.x * blockDim.x + threadIdx.x;  // (f, node4)
    const int total = F * 2048;
    if (i >= total) return;
    const int f  = i >> 11;           // / 2048
    const int n4 = i & 2047;
    const size_t base = (size_t)f * 8192 + (size_t)n4 * 4;
    const int MN = F * 8192;

    float4 s = *(const float4*)(P + base);
    for (int sp = 1; sp < SP; sp++) {
        float4 v = *(const float4*)(P + (size_t)sp * MN + base);
        s.x += v.x; s.y += v.y; s.z += v.z; s.w += v.w;
    }
    bf16x4 y0 = *(const bf16x4*)(Y0t + base);
    bf16x4 y1 = *(const bf16x4*)(Y1t + base);
    const float h0 = h[0], h1 = h[1], h2 = h[2], bb = bias[f];

    float v[4] = {s.x, s.y, s.z, s.w};
    #pragma unroll
    for (int r = 0; r < 4; r++) {
        float x = h0 * (float)y0[r] + h1 * (float)y1[r] + h2 * v[r] + bb;
        if (RELU) x = fmaxf(x, 0.0f);
        v[r] = x;
    }
    const int node = n4 * 4;
    if (F32OUT) {
        float* O = (float*)outp;
        #pragma unroll
        for (int r = 0; r < 4; r++) O[(size_t)(node + r) * F + f] = v[r];
    } else {
        __bf16* O = (__bf16*)outp;
        #pragma unroll
        for (int r = 0; r < 4; r++) O[(size_t)(node + r) * F + f] = (__bf16)v[r];
    }
}

extern "C" void kernel_launch(void* const* d_in, const int* in_sizes, int n_in,
                              void* d_out, int out_size, void* d_ws, size_t ws_size,
                              hipStream_t stream) {
    const float* S  = (const float*)d_in[0];
    const float* X  = (const float*)d_in[1];
    const float* W1 = (const float*)d_in[2];
    const float* h1 = (const float*)d_in[3];
    const float* b1 = (const float*)d_in[4];
    const float* W2 = (const float*)d_in[5];
    const float* h2 = (const float*)d_in[6];
    const float* b2 = (const float*)d_in[7];
    const float* W3 = (const float*)d_in[8];
    const float* h3 = (const float*)d_in[9];
    const float* b3 = (const float*)d_in[10];
    float* out = (float*)d_out;

    const int Nn = 8192, IN = 512, HID = 128, OUT = 64;

    char* ws = (char*)d_ws;
    size_t off = 0;
    auto carve = [&](size_t bytes) -> void* {
        void* p = ws + off;
        off += (bytes + 255) & ~(size_t)255;
        return p;
    };
    __bf16* Spk = (__bf16*)carve((size_t)Nn * Nn  * 2);   // 134.2 MB packed S
    __bf16* W1t = (__bf16*)carve((size_t)IN  * HID * 2);
    __bf16* W2t = (__bf16*)carve((size_t)HID * HID * 2);
    __bf16* W3t = (__bf16*)carve((size_t)HID * OUT * 2);
    __bf16* Y0t = (__bf16*)carve((size_t)HID * Nn * 2);   // [F][8192]
    __bf16* Y1t = (__bf16*)carve((size_t)HID * Nn * 2);
    __bf16* Act = (__bf16*)carve((size_t)Nn * HID * 2);   // [node][F]
    size_t  base = off;

    // split-K factor adaptive to remaining workspace (4 MB per split @F=128)
    const size_t per_split = (size_t)HID * Nn * 4;
    int SP = 1;
    while (SP < 8 && base + (size_t)(SP * 2) * per_split <= ws_size) SP *= 2;
    float* P = (float*)carve((size_t)SP * per_split);
    const int KCH = Nn / SP;

    // ---- pack S into per-(m,z) stream-order tiles (replaces convert) ----
    pack_S<<<dim3(Nn / 64, SP), dim3(256), 0, stream>>>(S, Spk, KCH, SP);
    // ---- tiny weight transposes ----
    cvt_transpose<<<dim3((IN * HID + 255) / 256), dim3(256), 0, stream>>>(W1, W1t, IN, HID);
    cvt_transpose<<<dim3((HID * HID + 255) / 256), dim3(256), 0, stream>>>(W2, W2t, HID, HID);
    cvt_transpose<<<dim3((HID * OUT + 255) / 256), dim3(256), 0, stream>>>(W3, W3t, HID, OUT);

    // S-GEMM: partials P[s][f][node]; grid (8192/64, 1, SP) = 1024 blocks
    auto sgemm = [&](const __bf16* Bt, int F) {
        if (F == 128)
            sgemm_lds<4><<<dim3(Nn / 64, 1, SP), dim3(256), 0, stream>>>(
                Spk, Bt, P, Nn, KCH, Nn);
        else
            sgemm_lds<2><<<dim3(Nn / 64, 1, SP), dim3(256), 0, stream>>>(
                Spk, Bt, P, Nn, KCH, Nn);
    };
    auto reduceY = [&](__bf16* Y, int F) {
        int t4 = F * 2048;
        reduce_partials<<<dim3((t4 + 255) / 256), dim3(256), 0, stream>>>(
            P, Y, t4, SP, F * Nn);
    };

    // ---- layer 1 ----
    // Y0t = W1t @ X (fp32 B, in-reg convert)   M=128, N=8192, K=512
    gemm_rd<2, 4, 1, 1><<<dim3(1, Nn / 64, 1), dim3(256), 0, stream>>>(
        W1t, X, Y0t, IN, IN, HID, Nn);
    sgemm(Y0t, HID);                       // P = split-partials of S@Y0
    reduceY(Y1t, HID);                     // Y1t = S@Y0
    sgemm(Y1t, HID);                       // P = split-partials of S@Y1
    combine_out<1, 0><<<dim3(HID * 2048 / 256), dim3(256), 0, stream>>>(
        P, Y0t, Y1t, h1, b1, Act, HID, SP);

    // ---- layer 2 ----
    gemm_rd<2, 4, 1, 0><<<dim3(1, Nn / 64, 1), dim3(256), 0, stream>>>(
        W2t, Act, Y0t, HID, HID, HID, Nn);
    sgemm(Y0t, HID);
    reduceY(Y1t, HID);
    sgemm(Y1t, HID);
    combine_out<1, 0><<<dim3(HID * 2048 / 256), dim3(256), 0, stream>>>(
        P, Y0t, Y1t, h2, b2, Act, HID, SP);

    // ---- layer 3 (F=64, fp32 out, no relu) ----
    gemm_rd<1, 4, 1, 0><<<dim3(1, Nn / 64, 1), dim3(256), 0, stream>>>(
        W3t, Act, Y0t, HID, HID, OUT, Nn);
    sgemm(Y0t, OUT);
    reduceY(Y1t, OUT);
    sgemm(Y1t, OUT);
    combine_out<0, 1><<<dim3(OUT * 2048 / 256), dim3(256), 0, stream>>>(
        P, Y0t, Y1t, h3, b3, out, OUT, SP);

    (void)in_sizes; (void)n_in; (void)out_size;
}